// Round 19
// baseline (217.682 us; speedup 1.0000x reference)
//
#include <hip/hip_runtime.h>
#include <hip/hip_bf16.h>

#define NN 16384
#define DD 128
#define KP1 11
#define NSPLIT 8
#define CBLK 32
#define COLS_PER_SPLIT (NN / NSPLIT)   /* 2048 */
#define NITER (COLS_PER_SPLIT / CBLK)  /* 64 */
#define GPITCH 1056                    /* 4-row group pitch: 1024B + 32B pad */

typedef __attribute__((ext_vector_type(8))) short bf16x8;
typedef __attribute__((ext_vector_type(4))) float f32x4;
typedef __attribute__((ext_vector_type(16))) float f32x16;
typedef unsigned int u32;

// ---------------------------------------------------------------------------
// Phase A: proj = feat @ W^T (fp32 exact), row L2 norm, bf16 normalized copy
// ---------------------------------------------------------------------------
__global__ __launch_bounds__(256) void phaseA_kernel(
    const float* __restrict__ feat, const float* __restrict__ W,
    float* __restrict__ proj, __hip_bfloat16* __restrict__ nrmb) {
  __shared__ float Wl[DD][132];
  __shared__ float fl[16][DD];
  const int t = threadIdx.x;
  const int blk = blockIdx.x;     // 16 rows per block

  const f32x4* W4 = (const f32x4*)W;
#pragma unroll
  for (int i = 0; i < 16; ++i) {
    int f4 = t + 256 * i;
    *(f32x4*)&Wl[f4 >> 5][(f4 & 31) * 4] = W4[f4];
  }
  const f32x4* F4 = (const f32x4*)(feat + (size_t)blk * 16 * DD);
#pragma unroll
  for (int i = 0; i < 2; ++i) {
    int f4 = t + 256 * i;
    *(f32x4*)&fl[f4 >> 5][(f4 & 31) * 4] = F4[f4];
  }
  __syncthreads();

  const int w = t >> 6, l = t & 63;
#pragma unroll 1
  for (int q = 0; q < 4; ++q) {
    const int rloc = w * 4 + q;
    const int r = blk * 16 + rloc;
    float a0 = 0.f, a1 = 0.f;
#pragma unroll
    for (int k = 0; k < DD; k += 4) {
      f32x4 fv = *(const f32x4*)&fl[rloc][k];
      f32x4 w0 = *(const f32x4*)&Wl[l][k];
      f32x4 w1 = *(const f32x4*)&Wl[l + 64][k];
      a0 += fv[0] * w0[0] + fv[1] * w0[1] + fv[2] * w0[2] + fv[3] * w0[3];
      a1 += fv[0] * w1[0] + fv[1] * w1[1] + fv[2] * w1[2] + fv[3] * w1[3];
    }
    float n2 = a0 * a0 + a1 * a1;
#pragma unroll
    for (int o = 32; o > 0; o >>= 1) n2 += __shfl_xor(n2, o);
    float invn = 1.0f / fmaxf(sqrtf(n2), 1e-12f);
    proj[(size_t)r * DD + l] = a0;
    proj[(size_t)r * DD + l + 64] = a1;
    nrmb[(size_t)r * DD + l] = __float2bfloat16(a0 * invn);
    nrmb[(size_t)r * DD + l + 64] = __float2bfloat16(a1 * invn);
  }
}

// ---------------------------------------------------------------------------
// Phase B: LDS-staged swapped-operand 32x32x16 MFMA Gram + branchless med3
// top-11 ladder. r18 audit: VALU issue ~130K cyc/SIMD, LDS pipe ~130K/CU,
// MFMA ~16K, wall 364K -> dominant stall = per-tile barrier lockstep.
// This round: ONE barrier per 2 tiles (4 LDS buffers: GRAM pair {0,1}
// while staging pair {2,3}), and accumulators init to 2.0f so the MFMA
// chain produces sim+2 directly (drops the per-insert v_add_f32; key =
// (bits(acc) & ~2047) | (2047 - local_idx), same semantics as r16-18).
// Conflicts 8.39M are structural to ds_read_b128 (constant across layouts,
// 0 in the no-LDS r17) -- not a lever. Grid 1024 = 4 blocks/CU exactly;
// register budget ~92 (VGPR+AGPR) pins 4 waves/SIMD (r9/r14: don't coerce).
// ---------------------------------------------------------------------------
#define LADDM(CKE)                                                         \
  { u32 ck = (CKE);                                                        \
    u32 n0 = k0 > ck ? k0 : ck;                                            \
    u32 n1, n2, n3, n4, n5, n6, n7, n8, n9, n10;                           \
    asm("v_med3_u32 %0,%1,%2,%3" : "=v"(n1) : "v"(ck), "v"(k1), "v"(k0));  \
    asm("v_med3_u32 %0,%1,%2,%3" : "=v"(n2) : "v"(ck), "v"(k2), "v"(k1));  \
    asm("v_med3_u32 %0,%1,%2,%3" : "=v"(n3) : "v"(ck), "v"(k3), "v"(k2));  \
    asm("v_med3_u32 %0,%1,%2,%3" : "=v"(n4) : "v"(ck), "v"(k4), "v"(k3));  \
    asm("v_med3_u32 %0,%1,%2,%3" : "=v"(n5) : "v"(ck), "v"(k5), "v"(k4));  \
    asm("v_med3_u32 %0,%1,%2,%3" : "=v"(n6) : "v"(ck), "v"(k6), "v"(k5));  \
    asm("v_med3_u32 %0,%1,%2,%3" : "=v"(n7) : "v"(ck), "v"(k7), "v"(k6));  \
    asm("v_med3_u32 %0,%1,%2,%3" : "=v"(n8) : "v"(ck), "v"(k8), "v"(k7));  \
    asm("v_med3_u32 %0,%1,%2,%3" : "=v"(n9) : "v"(ck), "v"(k9), "v"(k8));  \
    asm("v_med3_u32 %0,%1,%2,%3" : "=v"(n10) : "v"(ck), "v"(k10), "v"(k9));\
    k0 = n0; k1 = n1; k2 = n2; k3 = n3; k4 = n4; k5 = n5;                  \
    k6 = n6; k7 = n7; k8 = n8; k9 = n9; k10 = n10; }

// vv is already sim+2 (acc bias) -> keybuild is just and+or
#define INS1(vv, off)                                                      \
  LADDM(((__float_as_uint(vv) & 0xFFFFF800u) | (u32)(loid - (off))))

// scan 16 acc elems of one tile: lane covers cand offsets
// {0..3,8..11,16..19,24..27} + 4*hi within the tile
#define SCAN16(ACC, TBASE)                                                 \
  { const int loid = 2047 - (TBASE) - 4 * hi;                              \
    INS1(ACC[0], 0)   INS1(ACC[1], 1)   INS1(ACC[2], 2)                    \
    INS1(ACC[3], 3)   INS1(ACC[4], 8)   INS1(ACC[5], 9)                    \
    INS1(ACC[6], 10)  INS1(ACC[7], 11)  INS1(ACC[8], 16)                   \
    INS1(ACC[9], 17)  INS1(ACC[10], 18) INS1(ACC[11], 19)                  \
    INS1(ACC[12], 24) INS1(ACC[13], 25) INS1(ACC[14], 26)                  \
    INS1(ACC[15], 27) }

// Gram of one 32-cand tile into named acc from static buffer index BI;
// acc starts at 2.0f so the result is sim+2 (exact fp32, monotone)
#define GRAM(ACC, BI)                                                      \
  { _Pragma("unroll")                                                      \
    for (int i_ = 0; i_ < 16; ++i_) ACC[i_] = 2.0f;                        \
    const char* cb_ = &candB[BI][0];                                       \
    __builtin_amdgcn_s_setprio(1);                                         \
    _Pragma("unroll")                                                      \
    for (int kt = 0; kt < 8; ++kt) {                                       \
      bf16x8 cv = *(const bf16x8*)(cb_ + dso[kt]);                         \
      ACC = __builtin_amdgcn_mfma_f32_32x32x16_bf16(cv, rowF[kt], ACC,     \
                                                    0, 0, 0);              \
    }                                                                      \
    __builtin_amdgcn_s_setprio(0); }

__device__ __forceinline__ void gload_lds16(const void* g, void* l) {
  __builtin_amdgcn_global_load_lds(
      (const __attribute__((address_space(1))) unsigned int*)g,
      (__attribute__((address_space(3))) unsigned int*)l, 16, 0, 0);
}

__global__ __launch_bounds__(256, 4) void phaseB_kernel(
    const __hip_bfloat16* __restrict__ nrmb, u32* __restrict__ tk) {
  __shared__ __align__(16) char candB[4][8 * GPITCH];  // 4 x 8448 = 33792 B
  const int t = threadIdx.x;
  const int w = t >> 6, l = t & 63;
  const int l31 = l & 31, hi = l >> 5;
  const int rb = blockIdx.x >> 3;          // 0..127 row-blocks (128 rows)
  const int cs = blockIdx.x & 7;           // col-split
  const int r0 = rb * 128 + w * 32;        // wave's 32 rows
  const int csbase = cs * COLS_PER_SPLIT;
  const unsigned short* nb = (const unsigned short*)nrmb;

  // B-operand frags: my row (r0+l31), k-chunk kt*16 + hi*8
  bf16x8 rowF[8];
#pragma unroll
  for (int kt = 0; kt < 8; ++kt)
    rowF[kt] = *(const bf16x8*)(nb + (size_t)(r0 + l31) * DD + kt * 16 + hi * 8);

  // per-lane swizzled LDS byte offsets for the 8 cand fragments (hoisted);
  // row r base = (r>>2)*GPITCH + (r&3)*256 (group-padded layout)
  const int swsalt = (l31 & 7);
  const int rbase = (l31 >> 2) * GPITCH + (l31 & 3) * 256;
  int dso[8];
#pragma unroll
  for (int kt = 0; kt < 8; ++kt)
    dso[kt] = rbase + (((kt * 2 + hi) ^ swsalt) << 4);

  u32 k0 = 0, k1 = 0, k2 = 0, k3 = 0, k4 = 0, k5 = 0,
      k6 = 0, k7 = 0, k8 = 0, k9 = 0, k10 = 0;

  // wave w stages cands [w*8, w*8+8); source chunk pre-swizzled ^(cl&7);
  // instruction j's 1KB block lands linearly at group base (w*2+j)*GPITCH
#define STAGE(bufidx, itile)                                                  \
  {                                                                           \
    const unsigned short* srcb = nb + (size_t)(csbase + (itile)*CBLK) * DD;   \
    _Pragma("unroll")                                                         \
    for (int j = 0; j < 2; ++j) {                                             \
      int cl = w * 8 + j * 4 + (l >> 4);                                      \
      int ch = (l & 15) ^ (cl & 7);                                           \
      gload_lds16(srcb + (size_t)cl * DD + ch * 8,                            \
                  &candB[bufidx][(w * 2 + j) * GPITCH]);                      \
    }                                                                         \
  }

  // prologue: tiles 0,1 into buffer pair {0,1}
  STAGE(0, 0);
  STAGE(1, 1);
  __syncthreads();

  f32x16 aA, aB;
#pragma unroll 1
  for (int tt = 0; tt < NITER; tt += 4) {
    // body P0: GRAM/SCAN tiles tt,tt+1 from bufs {0,1}; stage {2,3}
    if (tt + 2 < NITER) { STAGE(2, tt + 2); STAGE(3, tt + 3); }
    GRAM(aA, 0)
    GRAM(aB, 1)
    SCAN16(aA, tt * CBLK)
    SCAN16(aB, (tt + 1) * CBLK)
    __syncthreads();   // pair {2,3} landed; bufs {0,1} reads done
    // body P1: GRAM/SCAN tiles tt+2,tt+3 from bufs {2,3}; stage {0,1}
    if (tt + 4 < NITER) { STAGE(0, tt + 4); STAGE(1, tt + 5); }
    GRAM(aA, 2)
    GRAM(aB, 3)
    SCAN16(aA, (tt + 2) * CBLK)
    SCAN16(aB, (tt + 3) * CBLK)
    __syncthreads();   // pair {0,1} landed; bufs {2,3} reads done
  }

  // merge lane <-> lane+32 partial ladders (disjoint halves of same row)
  {
    int m0 = __shfl_xor((int)k0, 32);
    int m1 = __shfl_xor((int)k1, 32);
    int m2 = __shfl_xor((int)k2, 32);
    int m3 = __shfl_xor((int)k3, 32);
    int m4 = __shfl_xor((int)k4, 32);
    int m5 = __shfl_xor((int)k5, 32);
    int m6 = __shfl_xor((int)k6, 32);
    int m7 = __shfl_xor((int)k7, 32);
    int m8 = __shfl_xor((int)k8, 32);
    int m9 = __shfl_xor((int)k9, 32);
    int m10 = __shfl_xor((int)k10, 32);
    LADDM((u32)m0)
    LADDM((u32)m1)
    LADDM((u32)m2)
    LADDM((u32)m3)
    LADDM((u32)m4)
    LADDM((u32)m5)
    LADDM((u32)m6)
    LADDM((u32)m7)
    LADDM((u32)m8)
    LADDM((u32)m9)
    LADDM((u32)m10)
  }

  if (hi == 0) {
    const int myr = r0 + l31;
    u32* ov = tk + ((size_t)cs * NN + myr) * KP1;
    ov[0] = k0; ov[1] = k1; ov[2] = k2; ov[3] = k3; ov[4] = k4; ov[5] = k5;
    ov[6] = k6; ov[7] = k7; ov[8] = k8; ov[9] = k9; ov[10] = k10;
  }
#undef STAGE
}

// ---------------------------------------------------------------------------
// Phase C: merge 8x11 packed-key partial top-k per row, softmax (self
// masked), gather. One wave per row; 4 rows per block. fp32 output.
// key -> value = as_float(key & ~2047) - 2 ; idx = s*2048 + 2047 - (key&2047)
// ---------------------------------------------------------------------------
__global__ __launch_bounds__(256) void phaseC_kernel(
    const float* __restrict__ proj, const float* __restrict__ feat,
    const float* __restrict__ emb, const u32* __restrict__ tk,
    float* __restrict__ out) {
  const int t = threadIdx.x, w = t >> 6, l = t & 63;
  const int r = blockIdx.x * 4 + w;

  // 88 candidates in 2 lane-slots
  float v0, v1 = -3.0e38f;
  int i0, i1 = 0x7fffffff;
  {
    int j = l, s = j / KP1, k = j - s * KP1;
    u32 key = tk[((size_t)s * NN + r) * KP1 + k];
    v0 = __uint_as_float(key & 0xFFFFF800u) - 2.0f;
    i0 = (s << 11) + 2047 - (int)(key & 2047u);
  }
  if (l < 88 - 64) {
    int j = 64 + l, s = j / KP1, k = j - s * KP1;
    u32 key = tk[((size_t)s * NN + r) * KP1 + k];
    v1 = __uint_as_float(key & 0xFFFFF800u) - 2.0f;
    i1 = (s << 11) + 2047 - (int)(key & 2047u);
  }

  bool t0 = false, t1 = false;
  float selv[KP1]; int seli[KP1];
#pragma unroll
  for (int s = 0; s < KP1; ++s) {
    float bv = -3.0e38f; int bi = 0x7fffffff;
    if (!t0 && (v0 > bv || (v0 == bv && i0 < bi))) { bv = v0; bi = i0; }
    if (!t1 && (v1 > bv || (v1 == bv && i1 < bi))) { bv = v1; bi = i1; }
#pragma unroll
    for (int o = 32; o > 0; o >>= 1) {
      float ovv = __shfl_xor(bv, o);
      int obi = __shfl_xor(bi, o);
      if (ovv > bv || (ovv == bv && obi < bi)) { bv = ovv; bi = obi; }
    }
    selv[s] = bv; seli[s] = bi;
    if (!t0 && i0 == bi) t0 = true;
    else if (!t1 && i1 == bi) t1 = true;
  }

  float m = -3.0e38f;
#pragma unroll
  for (int s = 0; s < KP1; ++s)
    if (seli[s] != r) m = fmaxf(m, selv[s]);
  float den = 0.f; float wg[KP1];
#pragma unroll
  for (int s = 0; s < KP1; ++s) {
    float e = (seli[s] != r) ? __expf(selv[s] - m) : 0.f;
    wg[s] = e; den += e;
  }
  const float rden = 1.0f / den;

  float p0 = 0.f, p1 = 0.f;
#pragma unroll
  for (int s = 0; s < KP1; ++s) {
    const float* pr = proj + (size_t)seli[s] * DD;
    float ws = wg[s] * rden;
    p0 += ws * pr[l];
    p1 += ws * pr[l + 64];
  }
  out[(size_t)r * DD + l] = feat[(size_t)r * DD + l] + 0.1f * (p0 + emb[l]);
  out[(size_t)r * DD + l + 64] =
      feat[(size_t)r * DD + l + 64] + 0.1f * (p1 + emb[l + 64]);
}

// ---------------------------------------------------------------------------
extern "C" void kernel_launch(void* const* d_in, const int* in_sizes, int n_in,
                              void* d_out, int out_size, void* d_ws, size_t ws_size,
                              hipStream_t stream) {
  (void)in_sizes; (void)n_in; (void)out_size; (void)ws_size;
  const float* feat = (const float*)d_in[0];
  const float* W    = (const float*)d_in[1];
  const float* emb  = (const float*)d_in[2];
  float* out = (float*)d_out;

  char* ws = (char*)d_ws;
  float* proj          = (float*)ws;                                    // 8 MB
  __hip_bfloat16* nrmb = (__hip_bfloat16*)(ws + (size_t)NN * DD * 4);   // 4 MB
  u32* tk = (u32*)(ws + (size_t)NN * DD * 6);                           // 5.77 MB

  phaseA_kernel<<<NN / 16, 256, 0, stream>>>(feat, W, proj, nrmb);
  phaseB_kernel<<<128 * NSPLIT, 256, 0, stream>>>(nrmb, tk);
  phaseC_kernel<<<NN / 4, 256, 0, stream>>>(proj, feat, emb, tk, out);
}

// Round 20
// 214.549 us; speedup vs baseline: 1.0146x; 1.0146x over previous
//
#include <hip/hip_runtime.h>
#include <hip/hip_bf16.h>

#define NN 16384
#define DD 128
#define KP1 11
#define NSPLIT 8
#define COLS_PER_SPLIT (NN / NSPLIT)   /* 2048 */
#define NPAIR 64                       /* pair-rounds of 2x16 cands */

typedef __attribute__((ext_vector_type(8))) short bf16x8;
typedef __attribute__((ext_vector_type(4))) float f32x4;
typedef unsigned int u32;

// ---------------------------------------------------------------------------
// Phase A: proj = feat @ W^T (fp32 exact), row L2 norm, bf16 normalized copy
// ---------------------------------------------------------------------------
__global__ __launch_bounds__(256) void phaseA_kernel(
    const float* __restrict__ feat, const float* __restrict__ W,
    float* __restrict__ proj, __hip_bfloat16* __restrict__ nrmb) {
  __shared__ float Wl[DD][132];
  __shared__ float fl[16][DD];
  const int t = threadIdx.x;
  const int blk = blockIdx.x;     // 16 rows per block

  const f32x4* W4 = (const f32x4*)W;
#pragma unroll
  for (int i = 0; i < 16; ++i) {
    int f4 = t + 256 * i;
    *(f32x4*)&Wl[f4 >> 5][(f4 & 31) * 4] = W4[f4];
  }
  const f32x4* F4 = (const f32x4*)(feat + (size_t)blk * 16 * DD);
#pragma unroll
  for (int i = 0; i < 2; ++i) {
    int f4 = t + 256 * i;
    *(f32x4*)&fl[f4 >> 5][(f4 & 31) * 4] = F4[f4];
  }
  __syncthreads();

  const int w = t >> 6, l = t & 63;
#pragma unroll 1
  for (int q = 0; q < 4; ++q) {
    const int rloc = w * 4 + q;
    const int r = blk * 16 + rloc;
    float a0 = 0.f, a1 = 0.f;
#pragma unroll
    for (int k = 0; k < DD; k += 4) {
      f32x4 fv = *(const f32x4*)&fl[rloc][k];
      f32x4 w0 = *(const f32x4*)&Wl[l][k];
      f32x4 w1 = *(const f32x4*)&Wl[l + 64][k];
      a0 += fv[0] * w0[0] + fv[1] * w0[1] + fv[2] * w0[2] + fv[3] * w0[3];
      a1 += fv[0] * w1[0] + fv[1] * w1[1] + fv[2] * w1[2] + fv[3] * w1[3];
    }
    float n2 = a0 * a0 + a1 * a1;
#pragma unroll
    for (int o = 32; o > 0; o >>= 1) n2 += __shfl_xor(n2, o);
    float invn = 1.0f / fmaxf(sqrtf(n2), 1e-12f);
    proj[(size_t)r * DD + l] = a0;
    proj[(size_t)r * DD + l + 64] = a1;
    nrmb[(size_t)r * DD + l] = __float2bfloat16(a0 * invn);
    nrmb[(size_t)r * DD + l + 64] = __float2bfloat16(a1 * invn);
  }
}

// ---------------------------------------------------------------------------
// Phase B: 16x16x32 swapped-operand MFMA Gram + branchless med3 top-11.
// REGISTER-DIET layout to unlock 8 waves/SIMD (r16's 32x32 needed ~88 regs
// -> pinned 4 waves/SIMD; latency stalls dominated). Wave covers 16 rows
// (lane&15 = row); candidates split 4-way across lane quads ((lane>>4)*4+reg
// = cand in tile), merged by 2-stage shfl butterfly at the end. Per-lane
// state: rowF[4](16) + dso[4] + ladder(11) + f32x4 acc = ~55 regs <= 64.
// Tiles of 16 cands staged in pairs via global_load_lds (source pre-swizzled
// chunk = slot^(row&7); read dso = row*256 + ((ks*4+lh)^(row&7))*16 -- even
// 8-lane-per-slot-image spread). LDS 16KB -> 8 blocks/CU = 32 waves/CU.
// Grid 2048 = exactly 8 blocks/CU, single round. acc init 2.0f -> MFMA
// yields sim+2; key = (bits & ~2047) | (2047 - local_idx) == jax tie order.
// ---------------------------------------------------------------------------
#define LADDM(CKE)                                                         \
  { u32 ck = (CKE);                                                        \
    u32 n0 = k0 > ck ? k0 : ck;                                            \
    u32 n1, n2, n3, n4, n5, n6, n7, n8, n9, n10;                           \
    asm("v_med3_u32 %0,%1,%2,%3" : "=v"(n1) : "v"(ck), "v"(k1), "v"(k0));  \
    asm("v_med3_u32 %0,%1,%2,%3" : "=v"(n2) : "v"(ck), "v"(k2), "v"(k1));  \
    asm("v_med3_u32 %0,%1,%2,%3" : "=v"(n3) : "v"(ck), "v"(k3), "v"(k2));  \
    asm("v_med3_u32 %0,%1,%2,%3" : "=v"(n4) : "v"(ck), "v"(k4), "v"(k3));  \
    asm("v_med3_u32 %0,%1,%2,%3" : "=v"(n5) : "v"(ck), "v"(k5), "v"(k4));  \
    asm("v_med3_u32 %0,%1,%2,%3" : "=v"(n6) : "v"(ck), "v"(k6), "v"(k5));  \
    asm("v_med3_u32 %0,%1,%2,%3" : "=v"(n7) : "v"(ck), "v"(k7), "v"(k6));  \
    asm("v_med3_u32 %0,%1,%2,%3" : "=v"(n8) : "v"(ck), "v"(k8), "v"(k7));  \
    asm("v_med3_u32 %0,%1,%2,%3" : "=v"(n9) : "v"(ck), "v"(k9), "v"(k8));  \
    asm("v_med3_u32 %0,%1,%2,%3" : "=v"(n10) : "v"(ck), "v"(k10), "v"(k9));\
    k0 = n0; k1 = n1; k2 = n2; k3 = n3; k4 = n4; k5 = n5;                  \
    k6 = n6; k7 = n7; k8 = n8; k9 = n9; k10 = n10; }

// vv is already sim+2 (acc bias) -> keybuild is and+or only
#define INS1(vv, off)                                                      \
  LADDM(((__float_as_uint(vv) & 0xFFFFF800u) | (u32)(loid - (off))))

// one 16-cand tile: 4 chained MFMAs (K=128) + 4 inserts
#define DOTILE(CBP, tp, T)                                                 \
  { const char* cb_ = (CBP) + (T) * 4096;                                  \
    f32x4 acc;                                                             \
    acc[0] = 2.0f; acc[1] = 2.0f; acc[2] = 2.0f; acc[3] = 2.0f;            \
    __builtin_amdgcn_s_setprio(1);                                         \
    acc = __builtin_amdgcn_mfma_f32_16x16x32_bf16(                         \
        *(const bf16x8*)(cb_ + dso[0]), rowF[0], acc, 0, 0, 0);            \
    acc = __builtin_amdgcn_mfma_f32_16x16x32_bf16(                         \
        *(const bf16x8*)(cb_ + dso[1]), rowF[1], acc, 0, 0, 0);            \
    acc = __builtin_amdgcn_mfma_f32_16x16x32_bf16(                         \
        *(const bf16x8*)(cb_ + dso[2]), rowF[2], acc, 0, 0, 0);            \
    acc = __builtin_amdgcn_mfma_f32_16x16x32_bf16(                         \
        *(const bf16x8*)(cb_ + dso[3]), rowF[3], acc, 0, 0, 0);            \
    __builtin_amdgcn_s_setprio(0);                                         \
    const int loid = 2047 - ((tp) * 32 + (T) * 16) - lh * 4;               \
    INS1(acc[0], 0) INS1(acc[1], 1) INS1(acc[2], 2) INS1(acc[3], 3) }

__device__ __forceinline__ void gload_lds16(const void* g, void* l) {
  __builtin_amdgcn_global_load_lds(
      (const __attribute__((address_space(1))) unsigned int*)g,
      (__attribute__((address_space(3))) unsigned int*)l, 16, 0, 0);
}

__global__ __launch_bounds__(256, 8) void phaseB_kernel(
    const __hip_bfloat16* __restrict__ nrmb, u32* __restrict__ tk) {
  __shared__ __align__(16) char candB[2][8192];   // 2 pair-buffers = 16 KB
  const int t = threadIdx.x;
  const int w = t >> 6, l = t & 63;
  const int r16i = l & 15, lh = l >> 4;    // my row slot, my cand quad
  const int rb = blockIdx.x >> 3;          // 0..255 row-blocks (64 rows)
  const int cs = blockIdx.x & 7;           // col-split
  const int gr = rb * 64 + w * 16 + r16i;  // my row
  const int csbase = cs * COLS_PER_SPLIT;
  const unsigned short* nb = (const unsigned short*)nrmb;

  // B-operand frags: my row, k-chunk ks*32 + lh*8 (8 elems each)
  bf16x8 rowF[4];
#pragma unroll
  for (int ks = 0; ks < 4; ++ks)
    rowF[ks] = *(const bf16x8*)(nb + (size_t)gr * DD + ks * 32 + lh * 8);

  // LDS read offsets: row r16i, chunk c = ks*4+lh stored at slot c^(r&7)
  int dso[4];
#pragma unroll
  for (int ks = 0; ks < 4; ++ks)
    dso[ks] = r16i * 256 + (((ks * 4 + lh) ^ (r16i & 7)) << 4);

  // stage source lane offset (even instr): rowlocal lh, slot (l&15)^lh
  const int loffE = lh * 256 + ((r16i ^ lh) << 4);

  u32 k0 = 0, k1 = 0, k2 = 0, k3 = 0, k4 = 0, k5 = 0,
      k6 = 0, k7 = 0, k8 = 0, k9 = 0, k10 = 0;

  // wave w stages pair-instr {2w, 2w+1}: 8 cand rows (8w..8w+7 of 32)
#define STAGE(BI, tp)                                                         \
  {                                                                           \
    const char* sb = (const char*)nb +                                        \
                     ((size_t)(csbase + (tp) * 32) << 8) + w * 2048;          \
    gload_lds16(sb + loffE, &candB[BI][w * 2048]);                            \
    gload_lds16(sb + 1024 + (loffE ^ 64), &candB[BI][w * 2048 + 1024]);       \
  }

  STAGE(0, 0);
  __syncthreads();

#pragma unroll 1
  for (int tp = 0; tp < NPAIR; ++tp) {
    const int bi = tp & 1;
    if (tp + 1 < NPAIR) STAGE(bi ^ 1, tp + 1);
    const char* cbp = &candB[bi][0];
    DOTILE(cbp, tp, 0)
    DOTILE(cbp, tp, 1)
    __syncthreads();   // next pair landed; this buffer's reads done
  }

  // butterfly merge of the 4 per-quad partial ladders (same row)
#pragma unroll
  for (int d = 16; d <= 32; d <<= 1) {
    int m0 = __shfl_xor((int)k0, d);
    int m1 = __shfl_xor((int)k1, d);
    int m2 = __shfl_xor((int)k2, d);
    int m3 = __shfl_xor((int)k3, d);
    int m4 = __shfl_xor((int)k4, d);
    int m5 = __shfl_xor((int)k5, d);
    int m6 = __shfl_xor((int)k6, d);
    int m7 = __shfl_xor((int)k7, d);
    int m8 = __shfl_xor((int)k8, d);
    int m9 = __shfl_xor((int)k9, d);
    int m10 = __shfl_xor((int)k10, d);
    LADDM((u32)m0)
    LADDM((u32)m1)
    LADDM((u32)m2)
    LADDM((u32)m3)
    LADDM((u32)m4)
    LADDM((u32)m5)
    LADDM((u32)m6)
    LADDM((u32)m7)
    LADDM((u32)m8)
    LADDM((u32)m9)
    LADDM((u32)m10)
  }

  if (lh == 0) {
    u32* ov = tk + ((size_t)cs * NN + gr) * KP1;
    ov[0] = k0; ov[1] = k1; ov[2] = k2; ov[3] = k3; ov[4] = k4; ov[5] = k5;
    ov[6] = k6; ov[7] = k7; ov[8] = k8; ov[9] = k9; ov[10] = k10;
  }
#undef STAGE
}

// ---------------------------------------------------------------------------
// Phase C: merge 8x11 packed-key partial top-k per row, softmax (self
// masked), gather. One wave per row; 4 rows per block. fp32 output.
// key -> value = as_float(key & ~2047) - 2 ; idx = s*2048 + 2047 - (key&2047)
// ---------------------------------------------------------------------------
__global__ __launch_bounds__(256) void phaseC_kernel(
    const float* __restrict__ proj, const float* __restrict__ feat,
    const float* __restrict__ emb, const u32* __restrict__ tk,
    float* __restrict__ out) {
  const int t = threadIdx.x, w = t >> 6, l = t & 63;
  const int r = blockIdx.x * 4 + w;

  // 88 candidates in 2 lane-slots
  float v0, v1 = -3.0e38f;
  int i0, i1 = 0x7fffffff;
  {
    int j = l, s = j / KP1, k = j - s * KP1;
    u32 key = tk[((size_t)s * NN + r) * KP1 + k];
    v0 = __uint_as_float(key & 0xFFFFF800u) - 2.0f;
    i0 = (s << 11) + 2047 - (int)(key & 2047u);
  }
  if (l < 88 - 64) {
    int j = 64 + l, s = j / KP1, k = j - s * KP1;
    u32 key = tk[((size_t)s * NN + r) * KP1 + k];
    v1 = __uint_as_float(key & 0xFFFFF800u) - 2.0f;
    i1 = (s << 11) + 2047 - (int)(key & 2047u);
  }

  bool t0 = false, t1 = false;
  float selv[KP1]; int seli[KP1];
#pragma unroll
  for (int s = 0; s < KP1; ++s) {
    float bv = -3.0e38f; int bi = 0x7fffffff;
    if (!t0 && (v0 > bv || (v0 == bv && i0 < bi))) { bv = v0; bi = i0; }
    if (!t1 && (v1 > bv || (v1 == bv && i1 < bi))) { bv = v1; bi = i1; }
#pragma unroll
    for (int o = 32; o > 0; o >>= 1) {
      float ovv = __shfl_xor(bv, o);
      int obi = __shfl_xor(bi, o);
      if (ovv > bv || (ovv == bv && obi < bi)) { bv = ovv; bi = obi; }
    }
    selv[s] = bv; seli[s] = bi;
    if (!t0 && i0 == bi) t0 = true;
    else if (!t1 && i1 == bi) t1 = true;
  }

  float m = -3.0e38f;
#pragma unroll
  for (int s = 0; s < KP1; ++s)
    if (seli[s] != r) m = fmaxf(m, selv[s]);
  float den = 0.f; float wg[KP1];
#pragma unroll
  for (int s = 0; s < KP1; ++s) {
    float e = (seli[s] != r) ? __expf(selv[s] - m) : 0.f;
    wg[s] = e; den += e;
  }
  const float rden = 1.0f / den;

  float p0 = 0.f, p1 = 0.f;
#pragma unroll
  for (int s = 0; s < KP1; ++s) {
    const float* pr = proj + (size_t)seli[s] * DD;
    float ws = wg[s] * rden;
    p0 += ws * pr[l];
    p1 += ws * pr[l + 64];
  }
  out[(size_t)r * DD + l] = feat[(size_t)r * DD + l] + 0.1f * (p0 + emb[l]);
  out[(size_t)r * DD + l + 64] =
      feat[(size_t)r * DD + l + 64] + 0.1f * (p1 + emb[l + 64]);
}

// ---------------------------------------------------------------------------
extern "C" void kernel_launch(void* const* d_in, const int* in_sizes, int n_in,
                              void* d_out, int out_size, void* d_ws, size_t ws_size,
                              hipStream_t stream) {
  (void)in_sizes; (void)n_in; (void)out_size; (void)ws_size;
  const float* feat = (const float*)d_in[0];
  const float* W    = (const float*)d_in[1];
  const float* emb  = (const float*)d_in[2];
  float* out = (float*)d_out;

  char* ws = (char*)d_ws;
  float* proj          = (float*)ws;                                    // 8 MB
  __hip_bfloat16* nrmb = (__hip_bfloat16*)(ws + (size_t)NN * DD * 4);   // 4 MB
  u32* tk = (u32*)(ws + (size_t)NN * DD * 6);                           // 5.77 MB

  phaseA_kernel<<<NN / 16, 256, 0, stream>>>(feat, W, proj, nrmb);
  phaseB_kernel<<<256 * NSPLIT, 256, 0, stream>>>(nrmb, tk);
  phaseC_kernel<<<NN / 4, 256, 0, stream>>>(proj, feat, emb, tk, out);
}

// Round 21
// 183.909 us; speedup vs baseline: 1.1836x; 1.1666x over previous
//
#include <hip/hip_runtime.h>
#include <hip/hip_bf16.h>

#define NN 16384
#define DD 128
#define KP1 11
#define NSPLIT 8
#define CBLK 32
#define COLS_PER_SPLIT (NN / NSPLIT)   /* 2048 */
#define NITER (COLS_PER_SPLIT / CBLK)  /* 64 */
#define GPITCH 1056                    /* 4-row group pitch: 1024B + 32B pad */

typedef __attribute__((ext_vector_type(8))) short bf16x8;
typedef __attribute__((ext_vector_type(4))) float f32x4;
typedef __attribute__((ext_vector_type(16))) float f32x16;
typedef unsigned int u32;

// W LDS layout: row r, 16B-chunk kc stored at word offset r*132 + 4*(kc^(r>>3)).
// The XOR spreads each 8-lane alias class (stride-132 rows: l, l+8 same bank)
// across all 32 banks -> conflict-free b128 reads (enumerated: uniform).
#define WOFF(r, kc) ((r) * 132 + 4 * ((kc) ^ ((r) >> 3)))

// ---------------------------------------------------------------------------
// Phase A: proj = feat @ W^T (fp32 exact), row L2 norm, bf16 normalized copy.
// Register-blocked 4 rows x 2 cols per thread: W chunk read ONCE per k-chunk
// (was 4x), fl reads are same-row broadcasts (conflict-free). fp32 op order
// per (row,col) identical to prior rounds -> proj bitwise unchanged.
// ---------------------------------------------------------------------------
__global__ __launch_bounds__(256) void phaseA_kernel(
    const float* __restrict__ feat, const float* __restrict__ W,
    float* __restrict__ proj, __hip_bfloat16* __restrict__ nrmb) {
  __shared__ float Wl[DD * 132];
  __shared__ float fl[16][DD];
  const int t = threadIdx.x;
  const int blk = blockIdx.x;     // 16 rows per block

  const f32x4* W4 = (const f32x4*)W;
#pragma unroll
  for (int i = 0; i < 16; ++i) {
    int f4 = t + 256 * i;
    int r = f4 >> 5, kc = f4 & 31;
    *(f32x4*)&Wl[WOFF(r, kc)] = W4[f4];
  }
  const f32x4* F4 = (const f32x4*)(feat + (size_t)blk * 16 * DD);
#pragma unroll
  for (int i = 0; i < 2; ++i) {
    int f4 = t + 256 * i;
    *(f32x4*)&fl[f4 >> 5][(f4 & 31) * 4] = F4[f4];
  }
  __syncthreads();

  const int w = t >> 6, l = t & 63;
  float a0q[4] = {0.f, 0.f, 0.f, 0.f};
  float a1q[4] = {0.f, 0.f, 0.f, 0.f};
#pragma unroll 8
  for (int kc = 0; kc < 32; ++kc) {
    f32x4 w0 = *(const f32x4*)&Wl[WOFF(l, kc)];
    f32x4 w1 = *(const f32x4*)&Wl[WOFF(l + 64, kc)];
#pragma unroll
    for (int q = 0; q < 4; ++q) {
      f32x4 fv = *(const f32x4*)&fl[w * 4 + q][kc * 4];
      a0q[q] += fv[0] * w0[0] + fv[1] * w0[1] + fv[2] * w0[2] + fv[3] * w0[3];
      a1q[q] += fv[0] * w1[0] + fv[1] * w1[1] + fv[2] * w1[2] + fv[3] * w1[3];
    }
  }
#pragma unroll
  for (int q = 0; q < 4; ++q) {
    const int r = blk * 16 + w * 4 + q;
    float n2 = a0q[q] * a0q[q] + a1q[q] * a1q[q];
#pragma unroll
    for (int o = 32; o > 0; o >>= 1) n2 += __shfl_xor(n2, o);
    float invn = 1.0f / fmaxf(sqrtf(n2), 1e-12f);
    proj[(size_t)r * DD + l] = a0q[q];
    proj[(size_t)r * DD + l + 64] = a1q[q];
    nrmb[(size_t)r * DD + l] = __float2bfloat16(a0q[q] * invn);
    nrmb[(size_t)r * DD + l + 64] = __float2bfloat16(a1q[q] * invn);
  }
}

// ---------------------------------------------------------------------------
// Phase B: r18 champion verbatim (151.3 us measured) + acc-init-2.0f bias:
// MFMA C-in starts at 2.0 so the chain yields sim+2 directly; the per-insert
// v_add_f32 disappears. Key = (bits(acc) & ~2047) | (2047 - local_idx) ==
// (val desc, idx asc) == jax.lax.top_k ties. 20-round verdict: this 32x32
// swapped-operand + med3-ladder + dual-acc-pipeline structure at 4 waves/SIMD
// is the robust optimum (occupancy/barrier/layout/no-LDS attacks all refuted
// by A/B: r9/r14 spill, r17 TA-pipe, r19 overlap loss, r20 LDS-traffic 2x).
// ---------------------------------------------------------------------------
#define LADDM(CKE)                                                         \
  { u32 ck = (CKE);                                                        \
    u32 n0 = k0 > ck ? k0 : ck;                                            \
    u32 n1, n2, n3, n4, n5, n6, n7, n8, n9, n10;                           \
    asm("v_med3_u32 %0,%1,%2,%3" : "=v"(n1) : "v"(ck), "v"(k1), "v"(k0));  \
    asm("v_med3_u32 %0,%1,%2,%3" : "=v"(n2) : "v"(ck), "v"(k2), "v"(k1));  \
    asm("v_med3_u32 %0,%1,%2,%3" : "=v"(n3) : "v"(ck), "v"(k3), "v"(k2));  \
    asm("v_med3_u32 %0,%1,%2,%3" : "=v"(n4) : "v"(ck), "v"(k4), "v"(k3));  \
    asm("v_med3_u32 %0,%1,%2,%3" : "=v"(n5) : "v"(ck), "v"(k5), "v"(k4));  \
    asm("v_med3_u32 %0,%1,%2,%3" : "=v"(n6) : "v"(ck), "v"(k6), "v"(k5));  \
    asm("v_med3_u32 %0,%1,%2,%3" : "=v"(n7) : "v"(ck), "v"(k7), "v"(k6));  \
    asm("v_med3_u32 %0,%1,%2,%3" : "=v"(n8) : "v"(ck), "v"(k8), "v"(k7));  \
    asm("v_med3_u32 %0,%1,%2,%3" : "=v"(n9) : "v"(ck), "v"(k9), "v"(k8));  \
    asm("v_med3_u32 %0,%1,%2,%3" : "=v"(n10) : "v"(ck), "v"(k10), "v"(k9));\
    k0 = n0; k1 = n1; k2 = n2; k3 = n3; k4 = n4; k5 = n5;                  \
    k6 = n6; k7 = n7; k8 = n8; k9 = n9; k10 = n10; }

// vv is already sim+2 (acc bias) -> keybuild is and+or only
#define INS1(vv, off)                                                      \
  LADDM(((__float_as_uint(vv) & 0xFFFFF800u) | (u32)(loid - (off))))

// scan 16 acc elems of one tile: lane covers cand offsets
// {0..3,8..11,16..19,24..27} + 4*hi within the tile
#define SCAN16(ACC, TBASE)                                                 \
  { const int loid = 2047 - (TBASE) - 4 * hi;                              \
    INS1(ACC[0], 0)   INS1(ACC[1], 1)   INS1(ACC[2], 2)                    \
    INS1(ACC[3], 3)   INS1(ACC[4], 8)   INS1(ACC[5], 9)                    \
    INS1(ACC[6], 10)  INS1(ACC[7], 11)  INS1(ACC[8], 16)                   \
    INS1(ACC[9], 17)  INS1(ACC[10], 18) INS1(ACC[11], 19)                  \
    INS1(ACC[12], 24) INS1(ACC[13], 25) INS1(ACC[14], 26)                  \
    INS1(ACC[15], 27) }

// Gram of one 32-cand tile into named acc (buffer parity P is static);
// acc starts at 2.0f so the result is sim+2 (exact fp32, monotone)
#define GRAM(ACC, P)                                                       \
  { _Pragma("unroll")                                                      \
    for (int i_ = 0; i_ < 16; ++i_) ACC[i_] = 2.0f;                        \
    const char* cb_ = &candB[P][0];                                        \
    __builtin_amdgcn_s_setprio(1);                                         \
    _Pragma("unroll")                                                      \
    for (int kt = 0; kt < 8; ++kt) {                                       \
      bf16x8 cv = *(const bf16x8*)(cb_ + dso[kt]);                         \
      ACC = __builtin_amdgcn_mfma_f32_32x32x16_bf16(cv, rowF[kt], ACC,     \
                                                    0, 0, 0);              \
    }                                                                      \
    __builtin_amdgcn_s_setprio(0); }

__device__ __forceinline__ void gload_lds16(const void* g, void* l) {
  __builtin_amdgcn_global_load_lds(
      (const __attribute__((address_space(1))) unsigned int*)g,
      (__attribute__((address_space(3))) unsigned int*)l, 16, 0, 0);
}

__global__ __launch_bounds__(256, 4) void phaseB_kernel(
    const __hip_bfloat16* __restrict__ nrmb, u32* __restrict__ tk) {
  __shared__ __align__(16) char candB[2][8 * GPITCH];  // 2 x 8448 B
  const int t = threadIdx.x;
  const int w = t >> 6, l = t & 63;
  const int l31 = l & 31, hi = l >> 5;
  const int rb = blockIdx.x >> 3;          // 0..127 row-blocks (128 rows)
  const int cs = blockIdx.x & 7;           // col-split
  const int r0 = rb * 128 + w * 32;        // wave's 32 rows
  const int csbase = cs * COLS_PER_SPLIT;
  const unsigned short* nb = (const unsigned short*)nrmb;

  // B-operand frags: my row (r0+l31), k-chunk kt*16 + hi*8
  bf16x8 rowF[8];
#pragma unroll
  for (int kt = 0; kt < 8; ++kt)
    rowF[kt] = *(const bf16x8*)(nb + (size_t)(r0 + l31) * DD + kt * 16 + hi * 8);

  // per-lane swizzled LDS byte offsets for the 8 cand fragments (hoisted);
  // row r base = (r>>2)*GPITCH + (r&3)*256 (group-padded layout)
  const int swsalt = (l31 & 7);
  const int rbase = (l31 >> 2) * GPITCH + (l31 & 3) * 256;
  int dso[8];
#pragma unroll
  for (int kt = 0; kt < 8; ++kt)
    dso[kt] = rbase + (((kt * 2 + hi) ^ swsalt) << 4);

  u32 k0 = 0, k1 = 0, k2 = 0, k3 = 0, k4 = 0, k5 = 0,
      k6 = 0, k7 = 0, k8 = 0, k9 = 0, k10 = 0;

  // wave w stages cands [w*8, w*8+8); source chunk pre-swizzled ^(cl&7);
  // instruction j's 1KB block lands linearly at group base (w*2+j)*GPITCH
#define STAGE(bufidx, itile)                                                  \
  {                                                                           \
    const unsigned short* srcb = nb + (size_t)(csbase + (itile)*CBLK) * DD;   \
    _Pragma("unroll")                                                         \
    for (int j = 0; j < 2; ++j) {                                             \
      int cl = w * 8 + j * 4 + (l >> 4);                                      \
      int ch = (l & 15) ^ (cl & 7);                                           \
      gload_lds16(srcb + (size_t)cl * DD + ch * 8,                            \
                  &candB[bufidx][(w * 2 + j) * GPITCH]);                      \
    }                                                                         \
  }

  STAGE(0, 0);
  __syncthreads();

  f32x16 aA, aB;
#pragma unroll 1
  for (int tt = 0; tt < NITER / 2; ++tt) {
    const int t0 = 2 * tt;
    // body 0: candB[0] holds tile t0; compute aA; scan aB = tile t0-1
    if (t0 + 1 < NITER) STAGE(1, t0 + 1);
    GRAM(aA, 0)
    if (tt > 0) { SCAN16(aB, (t0 - 1) * CBLK) }
    __syncthreads();   // tile t0+1 landed; candB[0] reads done
    // body 1: candB[1] holds tile t0+1; compute aB; scan aA = tile t0
    if (t0 + 2 < NITER) STAGE(0, t0 + 2);
    GRAM(aB, 1)
    SCAN16(aA, t0 * CBLK)
    __syncthreads();   // tile t0+2 landed; candB[1] reads done
  }
  // epilogue: scan last tile (NITER-1), still in aB
  SCAN16(aB, (NITER - 1) * CBLK)

  // merge lane <-> lane+32 partial ladders (disjoint halves of same row)
  {
    int m0 = __shfl_xor((int)k0, 32);
    int m1 = __shfl_xor((int)k1, 32);
    int m2 = __shfl_xor((int)k2, 32);
    int m3 = __shfl_xor((int)k3, 32);
    int m4 = __shfl_xor((int)k4, 32);
    int m5 = __shfl_xor((int)k5, 32);
    int m6 = __shfl_xor((int)k6, 32);
    int m7 = __shfl_xor((int)k7, 32);
    int m8 = __shfl_xor((int)k8, 32);
    int m9 = __shfl_xor((int)k9, 32);
    int m10 = __shfl_xor((int)k10, 32);
    LADDM((u32)m0)
    LADDM((u32)m1)
    LADDM((u32)m2)
    LADDM((u32)m3)
    LADDM((u32)m4)
    LADDM((u32)m5)
    LADDM((u32)m6)
    LADDM((u32)m7)
    LADDM((u32)m8)
    LADDM((u32)m9)
    LADDM((u32)m10)
  }

  if (hi == 0) {
    const int myr = r0 + l31;
    u32* ov = tk + ((size_t)cs * NN + myr) * KP1;
    ov[0] = k0; ov[1] = k1; ov[2] = k2; ov[3] = k3; ov[4] = k4; ov[5] = k5;
    ov[6] = k6; ov[7] = k7; ov[8] = k8; ov[9] = k9; ov[10] = k10;
  }
#undef STAGE
}

// ---------------------------------------------------------------------------
// Phase C: merge 8x11 packed-key partial top-k per row, softmax (self
// masked), gather. One wave per row; 4 rows per block. fp32 output.
// key -> value = as_float(key & ~2047) - 2 ; idx = s*2048 + 2047 - (key&2047)
// ---------------------------------------------------------------------------
__global__ __launch_bounds__(256) void phaseC_kernel(
    const float* __restrict__ proj, const float* __restrict__ feat,
    const float* __restrict__ emb, const u32* __restrict__ tk,
    float* __restrict__ out) {
  const int t = threadIdx.x, w = t >> 6, l = t & 63;
  const int r = blockIdx.x * 4 + w;

  // 88 candidates in 2 lane-slots
  float v0, v1 = -3.0e38f;
  int i0, i1 = 0x7fffffff;
  {
    int j = l, s = j / KP1, k = j - s * KP1;
    u32 key = tk[((size_t)s * NN + r) * KP1 + k];
    v0 = __uint_as_float(key & 0xFFFFF800u) - 2.0f;
    i0 = (s << 11) + 2047 - (int)(key & 2047u);
  }
  if (l < 88 - 64) {
    int j = 64 + l, s = j / KP1, k = j - s * KP1;
    u32 key = tk[((size_t)s * NN + r) * KP1 + k];
    v1 = __uint_as_float(key & 0xFFFFF800u) - 2.0f;
    i1 = (s << 11) + 2047 - (int)(key & 2047u);
  }

  bool t0 = false, t1 = false;
  float selv[KP1]; int seli[KP1];
#pragma unroll
  for (int s = 0; s < KP1; ++s) {
    float bv = -3.0e38f; int bi = 0x7fffffff;
    if (!t0 && (v0 > bv || (v0 == bv && i0 < bi))) { bv = v0; bi = i0; }
    if (!t1 && (v1 > bv || (v1 == bv && i1 < bi))) { bv = v1; bi = i1; }
#pragma unroll
    for (int o = 32; o > 0; o >>= 1) {
      float ovv = __shfl_xor(bv, o);
      int obi = __shfl_xor(bi, o);
      if (ovv > bv || (ovv == bv && obi < bi)) { bv = ovv; bi = obi; }
    }
    selv[s] = bv; seli[s] = bi;
    if (!t0 && i0 == bi) t0 = true;
    else if (!t1 && i1 == bi) t1 = true;
  }

  float m = -3.0e38f;
#pragma unroll
  for (int s = 0; s < KP1; ++s)
    if (seli[s] != r) m = fmaxf(m, selv[s]);
  float den = 0.f; float wg[KP1];
#pragma unroll
  for (int s = 0; s < KP1; ++s) {
    float e = (seli[s] != r) ? __expf(selv[s] - m) : 0.f;
    wg[s] = e; den += e;
  }
  const float rden = 1.0f / den;

  float p0 = 0.f, p1 = 0.f;
#pragma unroll
  for (int s = 0; s < KP1; ++s) {
    const float* pr = proj + (size_t)seli[s] * DD;
    float ws = wg[s] * rden;
    p0 += ws * pr[l];
    p1 += ws * pr[l + 64];
  }
  out[(size_t)r * DD + l] = feat[(size_t)r * DD + l] + 0.1f * (p0 + emb[l]);
  out[(size_t)r * DD + l + 64] =
      feat[(size_t)r * DD + l + 64] + 0.1f * (p1 + emb[l + 64]);
}

// ---------------------------------------------------------------------------
extern "C" void kernel_launch(void* const* d_in, const int* in_sizes, int n_in,
                              void* d_out, int out_size, void* d_ws, size_t ws_size,
                              hipStream_t stream) {
  (void)in_sizes; (void)n_in; (void)out_size; (void)ws_size;
  const float* feat = (const float*)d_in[0];
  const float* W    = (const float*)d_in[1];
  const float* emb  = (const float*)d_in[2];
  float* out = (float*)d_out;

  char* ws = (char*)d_ws;
  float* proj          = (float*)ws;                                    // 8 MB
  __hip_bfloat16* nrmb = (__hip_bfloat16*)(ws + (size_t)NN * DD * 4);   // 4 MB
  u32* tk = (u32*)(ws + (size_t)NN * DD * 6);                           // 5.77 MB

  phaseA_kernel<<<NN / 16, 256, 0, stream>>>(feat, W, proj, nrmb);
  phaseB_kernel<<<128 * NSPLIT, 256, 0, stream>>>(nrmb, tk);
  phaseC_kernel<<<NN / 4, 256, 0, stream>>>(proj, feat, emb, tk, out);
}